// Round 7
// baseline (555.509 us; speedup 1.0000x reference)
//
#include <hip/hip_runtime.h>
#include <hip/hip_bf16.h>

typedef __bf16 bf16;
typedef __bf16 bf16x8 __attribute__((ext_vector_type(8)));
typedef float f32x4 __attribute__((ext_vector_type(4)));

// problem sizes
#define NN 8192
#define DIN 128
#define DTH 256
#define DH 64

// workspace layout (bytes)
#define OFF_BN   0                                // 256 f32 bn sums (1 KB)
#define OFF_PDEN 1024                             // 8192 f32 row denominators
#define ZERO_BYTES (1024 + 8192*4)                // bn + pden zeroed
#define OFF_PACC 65536                            // 16 ks * 8192 * 64 f32 = 32 MB
#define OFF_HX   (OFF_PACC + 16*8192*64*4)        // 8192*256 bf16 Hx (4 MB)
#define OFF_X2T  (OFF_HX + 8192*256*2)            // 64*8192 bf16 X2T (1 MB)
#define OFF_PG   (OFF_X2T + 64*8192*2)            // 8192*8192 bf16 P (128 MB)

#define E_CONST 2.71828182845904523f

__device__ __forceinline__ void gl_lds16(const bf16* g, bf16* l) {
    __builtin_amdgcn_global_load_lds(
        (const __attribute__((address_space(1))) void*)g,
        (__attribute__((address_space(3))) void*)l, 16, 0, 0);
}

// ---------------------------------------------------------------------------
__global__ __launch_bounds__(256) void k_bn_stats(const float* __restrict__ H,
                                                  float* __restrict__ bns) {
    __shared__ float s1[256], s2[256];
    int t = threadIdx.x;
    int f = t & 127, rh = t >> 7;
    int r0 = blockIdx.x * 32 + rh * 16;
    float a = 0.f, b = 0.f;
#pragma unroll
    for (int rr = 0; rr < 16; ++rr) {
        float x = H[(size_t)(r0 + rr) * DIN + f];
        a += x; b += x * x;
    }
    s1[t] = a; s2[t] = b;
    __syncthreads();
    if (t < 128) {
        atomicAdd(&bns[f], s1[t] + s1[t + 128]);
        atomicAdd(&bns[128 + f], s2[t] + s2[t + 128]);
    }
}

// ---------------------------------------------------------------------------
__global__ __launch_bounds__(256) void k_project(
    const float* __restrict__ H, const float* __restrict__ bns,
    const float* __restrict__ gamma, const float* __restrict__ beta,
    const float* __restrict__ Wt, const float* __restrict__ bt,
    const float* __restrict__ W1, const float* __restrict__ b1,
    const float* __restrict__ W2, const float* __restrict__ b2,
    bf16* __restrict__ Hx, bf16* __restrict__ X2T, float* __restrict__ out)
{
    __shared__ float Hn[16 * 128];
    int t = threadIdx.x;
    int r0 = blockIdx.x * 16;
    {
        int f = t & 127;
        float mean = bns[f] * (1.f / 8192.f);
        float var  = bns[128 + f] * (1.f / 8192.f) - mean * mean;
        float sc = rsqrtf(var + 1e-5f) * gamma[f];
        float sh = beta[f];
        int rb = t >> 7;
#pragma unroll
        for (int p = 0; p < 8; ++p) {
            int row = rb + p * 2;
            float x = H[(size_t)(r0 + row) * DIN + f];
            Hn[row * 128 + f] = (x - mean) * sc + sh;
        }
    }
    __syncthreads();
    {
        int c0 = t & 63, rg = t >> 6;
        float acc[4][4];
#pragma unroll
        for (int i = 0; i < 4; ++i)
#pragma unroll
            for (int j = 0; j < 4; ++j) acc[i][j] = 0.f;
        for (int k = 0; k < 128; ++k) {
            float h[4];
#pragma unroll
            for (int rr = 0; rr < 4; ++rr) h[rr] = Hn[(rg * 4 + rr) * 128 + k];
#pragma unroll
            for (int cc = 0; cc < 4; ++cc) {
                float wv = Wt[k * DTH + c0 + 64 * cc];
#pragma unroll
                for (int rr = 0; rr < 4; ++rr) acc[rr][cc] += h[rr] * wv;
            }
        }
#pragma unroll
        for (int rr = 0; rr < 4; ++rr) {
            int row = r0 + rg * 4 + rr;
#pragma unroll
            for (int cc = 0; cc < 4; ++cc) {
                int c = c0 + 64 * cc;
                Hx[(size_t)row * DTH + c] = (bf16)(acc[rr][cc] + bt[c]);
            }
        }
    }
    {
        int c = t & 63, rg = t >> 6;
        float a1[4] = {0,0,0,0}, a2[4] = {0,0,0,0};
        for (int k = 0; k < 128; ++k) {
            float w1 = W1[k * DH + c], w2 = W2[k * DH + c];
#pragma unroll
            for (int rr = 0; rr < 4; ++rr) {
                float h = Hn[(rg * 4 + rr) * 128 + k];
                a1[rr] += h * w1; a2[rr] += h * w2;
            }
        }
#pragma unroll
        for (int rr = 0; rr < 4; ++rr) {
            int row = r0 + rg * 4 + rr;
            float v1 = a1[rr] + b1[c];
            out[(size_t)row * 128 + c] = v1 > 0.f ? v1 : 0.01f * v1;
            X2T[(size_t)c * NN + row] = (bf16)(a2[rr] + b2[c]);
        }
    }
}

// ---------------------------------------------------------------------------
// k_score: 128x128-tile GEMM S = Hx @ Hx^T (K=256, BK=64, double-buffered
// global_load_lds with XOR chunk swizzle) + fused epilogue:
// w = mask ? exp(sigmoid(s)) : 0, diag = e; row-sum -> atomicAdd pden;
// P stored bf16 to global. Grid 4096 (64x64 tiles) -> 16 block generations.
// Counted vmcnt(16) barriers: issue order per step is [stage 8][av 16], so
// vmcnt(16) completes the stage DMAs while the A-mask loads stay in flight.
__global__ __launch_bounds__(256, 2) void k_score(
    const float* __restrict__ A, const bf16* __restrict__ Hx,
    bf16* __restrict__ Pg, float* __restrict__ pden)
{
    __shared__ __align__(16) bf16 bufA[2][128 * 64];   // 16 KB each
    __shared__ __align__(16) bf16 bufB[2][128 * 64];

    int t = threadIdx.x;
    int w = t >> 6, l = t & 63;
    int q = l >> 4, li = l & 15;
    int bid = blockIdx.x;
    int rid = (bid & 7) * 512 + (bid >> 3);   // XCD swizzle, bijective
    int it = rid >> 6, jt = rid & 63;
    int i0 = it * 128, j0 = jt * 128;
    int wr = w >> 1, wc = w & 1;              // wave quadrant (2x2 of 64x64)

    int sr = t >> 3, sc = t & 7;              // staging: row-sub, chunk col

    // stage both 128x64 tiles for k-step S into buffer PAR.
    // LDS linear: chunk u = p*256+t -> (row u>>3, chunk u&7); source chunk
    // pre-swizzled (c ^ (row&7)) so reads below are conflict-free.
#define SCORE_STAGE(PAR, S) {                                                  \
        _Pragma("unroll")                                                      \
        for (int p = 0; p < 4; ++p) {                                          \
            int r_ = p * 32 + sr;                                              \
            gl_lds16(Hx + (size_t)(i0 + r_) * DTH + (S) * 64 + ((sc ^ (r_ & 7)) << 3), \
                     &bufA[PAR][(p * 256 + t) * 8]);                           \
        }                                                                      \
        _Pragma("unroll")                                                      \
        for (int p = 0; p < 4; ++p) {                                          \
            int r_ = p * 32 + sr;                                              \
            gl_lds16(Hx + (size_t)(j0 + r_) * DTH + (S) * 64 + ((sc ^ (r_ & 7)) << 3), \
                     &bufB[PAR][(p * 256 + t) * 8]);                           \
        } }

    // A-mask batch for m-fragment MF: 16 scalar dwords (64B-coalesced per li)
#define SCORE_AV(DST, MF) {                                                    \
        _Pragma("unroll")                                                      \
        for (int nf = 0; nf < 4; ++nf)                                         \
            _Pragma("unroll")                                                  \
            for (int r = 0; r < 4; ++r)                                        \
                DST[nf * 4 + r] = A[(size_t)(i0 + wr * 64 + (MF) * 16 + q * 4 + r) * NN \
                                    + j0 + wc * 64 + nf * 16 + li];            \
    }

    float av0[16], av1[16], av2[16], av3[16];
    f32x4 acc[4][4];
#pragma unroll
    for (int mf = 0; mf < 4; ++mf)
#pragma unroll
        for (int nf = 0; nf < 4; ++nf)
            acc[mf][nf] = (f32x4){0.f, 0.f, 0.f, 0.f};

    // prologue
    SCORE_STAGE(0, 0)
    asm volatile("s_waitcnt vmcnt(0)" ::: "memory");
    __builtin_amdgcn_s_barrier();

#define SCORE_STEP(S, PAR, AVD) {                                              \
        if ((S) < 3) SCORE_STAGE((PAR) ^ 1, (S) + 1)                           \
        __builtin_amdgcn_sched_barrier(0);                                     \
        SCORE_AV(AVD, S)                                                       \
        __builtin_amdgcn_sched_barrier(0);                                     \
        _Pragma("unroll")                                                      \
        for (int kk = 0; kk < 2; ++kk) {                                       \
            bf16x8 aR[4], bR[4];                                               \
            _Pragma("unroll")                                                  \
            for (int mf = 0; mf < 4; ++mf)                                     \
                aR[mf] = *(const bf16x8*)&bufA[PAR][(wr * 64 + mf * 16 + li) * 64 \
                                                    + (((kk * 4 + q) ^ (li & 7)) << 3)]; \
            _Pragma("unroll")                                                  \
            for (int nf = 0; nf < 4; ++nf)                                     \
                bR[nf] = *(const bf16x8*)&bufB[PAR][(wc * 64 + nf * 16 + li) * 64 \
                                                    + (((kk * 4 + q) ^ (li & 7)) << 3)]; \
            _Pragma("unroll")                                                  \
            for (int mf = 0; mf < 4; ++mf)                                     \
                _Pragma("unroll")                                              \
                for (int nf = 0; nf < 4; ++nf)                                 \
                    acc[mf][nf] = __builtin_amdgcn_mfma_f32_16x16x32_bf16(aR[mf], bR[nf], acc[mf][nf], 0, 0, 0); \
        }                                                                      \
        if ((S) < 3) {                                                         \
            asm volatile("s_waitcnt vmcnt(16)" ::: "memory");                  \
            __builtin_amdgcn_s_barrier();                                      \
        } }

    SCORE_STEP(0, 0, av0)
    SCORE_STEP(1, 1, av1)
    SCORE_STEP(2, 0, av2)
    SCORE_STEP(3, 1, av3)

    asm volatile("s_waitcnt vmcnt(0)" ::: "memory");   // av3 complete

    // epilogue: gate + diag + P store + row-sum atomics (no barriers needed)
#define SCORE_EPI(MF, AVD) {                                                   \
        float rs0 = 0.f, rs1 = 0.f, rs2 = 0.f, rs3 = 0.f;                      \
        _Pragma("unroll")                                                      \
        for (int nf = 0; nf < 4; ++nf) {                                       \
            _Pragma("unroll")                                                  \
            for (int r = 0; r < 4; ++r) {                                      \
                int ig = i0 + wr * 64 + (MF) * 16 + q * 4 + r;                 \
                int jc = j0 + wc * 64 + nf * 16 + li;                          \
                float s = acc[MF][nf][r];                                      \
                float sig = __builtin_amdgcn_rcpf(1.f + __expf(-s));           \
                float wv = (AVD[nf * 4 + r] > 0.f) ? __expf(sig) : 0.f;        \
                if (ig == jc) wv = E_CONST;                                    \
                if (r == 0) rs0 += wv; else if (r == 1) rs1 += wv;             \
                else if (r == 2) rs2 += wv; else rs3 += wv;                    \
                Pg[(size_t)ig * NN + jc] = (bf16)wv;                           \
            }                                                                  \
        }                                                                      \
        float rsv[4] = {rs0, rs1, rs2, rs3};                                   \
        _Pragma("unroll")                                                      \
        for (int ri = 0; ri < 4; ++ri) {                                       \
            float v = rsv[ri];                                                 \
            v += __shfl_xor(v, 1, 64);                                         \
            v += __shfl_xor(v, 2, 64);                                         \
            v += __shfl_xor(v, 4, 64);                                         \
            v += __shfl_xor(v, 8, 64);                                         \
            if (li == 0)                                                       \
                atomicAdd(&pden[i0 + wr * 64 + (MF) * 16 + q * 4 + ri], v);    \
        } }

    SCORE_EPI(0, av0)
    SCORE_EPI(1, av1)
    SCORE_EPI(2, av2)
    SCORE_EPI(3, av3)
#undef SCORE_STAGE
#undef SCORE_AV
#undef SCORE_STEP
#undef SCORE_EPI
}

// ---------------------------------------------------------------------------
// k_out2: out2-partials = P @ X2 (split-K). LDS-free, barrier-free: each
// wave's P rows are wave-private register fragments; X2T rows are the B
// fragments directly. Grid 64 i-tiles x 16 k-splits = 1024 -> 4 blocks/CU.
// Pure HBM stream of P (128 MB) with 1-chunk-deep ping-pong prefetch.
__global__ __launch_bounds__(256, 4) void k_out2(
    const bf16* __restrict__ Pg, const bf16* __restrict__ X2T,
    float* __restrict__ pacc)
{
    int t = threadIdx.x;
    int w = t >> 6, l = t & 63;
    int q = l >> 4, li = l & 15;
    int bid = blockIdx.x;
    int ks = bid & 15, it = bid >> 4;
    size_t k0 = (size_t)ks * 512;
    int i0 = it * 128;

    const bf16* prow = Pg  + (size_t)(i0 + w * 32 + li) * NN + k0 + q * 8;
    const bf16* xrow = X2T + (size_t)li * NN + k0 + q * 8;

    f32x4 acc[2][4];
#pragma unroll
    for (int mb = 0; mb < 2; ++mb)
#pragma unroll
        for (int cb = 0; cb < 4; ++cb)
            acc[mb][cb] = (f32x4){0.f, 0.f, 0.f, 0.f};

#define LOADP(PA, XB, CH) {                                                    \
        _Pragma("unroll")                                                      \
        for (int mb = 0; mb < 2; ++mb)                                         \
            PA[mb] = *(const bf16x8*)(prow + (size_t)mb * 16 * NN + (CH) * 32); \
        _Pragma("unroll")                                                      \
        for (int cb = 0; cb < 4; ++cb)                                         \
            XB[cb] = *(const bf16x8*)(xrow + (size_t)cb * 16 * NN + (CH) * 32); \
    }
#define MM(PA, XB)                                                             \
        _Pragma("unroll")                                                      \
        for (int mb = 0; mb < 2; ++mb)                                         \
            _Pragma("unroll")                                                  \
            for (int cb = 0; cb < 4; ++cb)                                     \
                acc[mb][cb] = __builtin_amdgcn_mfma_f32_16x16x32_bf16(PA[mb], XB[cb], acc[mb][cb], 0, 0, 0);

    bf16x8 paE[2], xbE[4], paO[2], xbO[4];
    LOADP(paE, xbE, 0)
    for (int ch = 0; ch < 16; ch += 2) {
        if (ch + 1 < 16) LOADP(paO, xbO, ch + 1)
        MM(paE, xbE)
        if (ch + 2 < 16) LOADP(paE, xbE, ch + 2)
        MM(paO, xbO)
    }
#undef LOADP
#undef MM

    // store partials: pacc[ks][row][col]
    float* po = pacc + (size_t)ks * NN * DH;
#pragma unroll
    for (int mb = 0; mb < 2; ++mb)
#pragma unroll
        for (int cb = 0; cb < 4; ++cb)
#pragma unroll
            for (int r = 0; r < 4; ++r)
                po[(size_t)(i0 + w * 32 + mb * 16 + q * 4 + r) * DH + cb * 16 + li] =
                    acc[mb][cb][r];
}

// ---------------------------------------------------------------------------
__global__ __launch_bounds__(256) void k_finalize(const float* __restrict__ pacc,
                                                  const float* __restrict__ pden,
                                                  float* __restrict__ out)
{
    int e = blockIdx.x * 256 + threadIdx.x;
    int i = e >> 6, c = e & 63;
    float s = 0.f;
#pragma unroll
    for (int ks = 0; ks < 16; ++ks)
        s += pacc[(size_t)ks * NN * DH + e];
    float v = s / pden[i];
    out[(size_t)i * 128 + 64 + c] = v > 0.f ? v : 0.01f * v;
}

// ---------------------------------------------------------------------------
extern "C" void kernel_launch(void* const* d_in, const int* in_sizes, int n_in,
                              void* d_out, int out_size, void* d_ws, size_t ws_size,
                              hipStream_t stream)
{
    const float* H     = (const float*)d_in[0];
    const float* A     = (const float*)d_in[1];
    const float* gamma = (const float*)d_in[2];
    const float* beta  = (const float*)d_in[3];
    const float* Wt    = (const float*)d_in[4];
    const float* bt    = (const float*)d_in[5];
    const float* W1    = (const float*)d_in[6];
    const float* b1    = (const float*)d_in[7];
    const float* W2    = (const float*)d_in[8];
    const float* b2    = (const float*)d_in[9];
    float* out = (float*)d_out;

    char* ws = (char*)d_ws;
    float* bns  = (float*)(ws + OFF_BN);
    float* pden = (float*)(ws + OFF_PDEN);
    float* pacc = (float*)(ws + OFF_PACC);
    bf16*  Hx   = (bf16*)(ws + OFF_HX);
    bf16*  X2T  = (bf16*)(ws + OFF_X2T);
    bf16*  Pg   = (bf16*)(ws + OFF_PG);

    hipMemsetAsync(ws, 0, ZERO_BYTES, stream);
    k_bn_stats<<<256, 256, 0, stream>>>(H, bns);
    k_project<<<512, 256, 0, stream>>>(H, bns, gamma, beta, Wt, bt, W1, b1, W2, b2,
                                       Hx, X2T, out);
    k_score<<<4096, 256, 0, stream>>>(A, Hx, Pg, pden);
    k_out2<<<1024, 256, 0, stream>>>(Pg, X2T, pacc);
    k_finalize<<<2048, 256, 0, stream>>>(pacc, pden, out);
}

// Round 8
// 554.202 us; speedup vs baseline: 1.0024x; 1.0024x over previous
//
#include <hip/hip_runtime.h>
#include <hip/hip_bf16.h>

typedef __bf16 bf16;
typedef __bf16 bf16x8 __attribute__((ext_vector_type(8)));
typedef float f32x4 __attribute__((ext_vector_type(4)));

// problem sizes
#define NN 8192
#define DIN 128
#define DTH 256
#define DH 64

// workspace layout (bytes)
#define OFF_PACC 0                         // 8192*64 f32 partial aggregation
#define OFF_PDEN (8192*64*4)               // 8192 f32 partial denominators
#define OFF_BN   (OFF_PDEN + 8192*4)       // 256 f32 bn sums (sum, sumsq)
#define OFF_HX   (OFF_BN + 1024)           // 8192*256 bf16 Hx
#define OFF_X2T  (OFF_HX + 8192*256*2)     // 64*8192 bf16 X2 transposed
#define OFF_AM   (OFF_X2T + 64*8192*2)     // 8192*128 u64 adjacency bitmask (8 MB)
#define ZERO_BYTES OFF_HX

// ---------------------------------------------------------------------------
// Pack adjacency to bits with full coalescing: lane l of a wave tests
// A[row][s*64 + l] > 0; __ballot gives the u64 word for 64 consecutive cols.
// 256 MB read as coalesced 256B/wave-instr -> streams at HBM rate.
__global__ __launch_bounds__(256) void k_pack(const float* __restrict__ A,
                                              unsigned long long* __restrict__ Am)
{
    int row = blockIdx.x;
    int w = threadIdx.x >> 6, l = threadIdx.x & 63;
    const float* p = A + (size_t)row * NN;
    unsigned long long* po = Am + (size_t)row * 128;
#pragma unroll 4
    for (int s = w * 32; s < w * 32 + 32; ++s) {
        float v = p[s * 64 + l];
        unsigned long long m = __ballot(v > 0.f);
        if (l == 0) po[s] = m;
    }
}

// ---------------------------------------------------------------------------
// BN statistics: per-feature sum and sum-of-squares via per-block partials.
__global__ __launch_bounds__(256) void k_bn_stats(const float* __restrict__ H,
                                                  float* __restrict__ bns) {
    __shared__ float s1[256], s2[256];
    int t = threadIdx.x;
    int f = t & 127, rh = t >> 7;
    int r0 = blockIdx.x * 32 + rh * 16;
    float a = 0.f, b = 0.f;
#pragma unroll
    for (int rr = 0; rr < 16; ++rr) {
        float x = H[(size_t)(r0 + rr) * DIN + f];
        a += x; b += x * x;
    }
    s1[t] = a; s2[t] = b;
    __syncthreads();
    if (t < 128) {
        atomicAdd(&bns[f], s1[t] + s1[t + 128]);
        atomicAdd(&bns[128 + f], s2[t] + s2[t + 128]);
    }
}

// ---------------------------------------------------------------------------
// BN apply + projections: Hx = Hn@Wt+bt (bf16), out1 = leaky(Hn@W1+b1) (fp32,
// written directly to left half of output), X2T[c][row] = Hn@W2+b2 (bf16).
__global__ __launch_bounds__(256) void k_project(
    const float* __restrict__ H, const float* __restrict__ bns,
    const float* __restrict__ gamma, const float* __restrict__ beta,
    const float* __restrict__ Wt, const float* __restrict__ bt,
    const float* __restrict__ W1, const float* __restrict__ b1,
    const float* __restrict__ W2, const float* __restrict__ b2,
    bf16* __restrict__ Hx, bf16* __restrict__ X2T, float* __restrict__ out)
{
    __shared__ float Hn[16 * 128];
    int t = threadIdx.x;
    int r0 = blockIdx.x * 16;
    {   // BN apply: each thread owns feature f = t&127, rows t>>7 + 2p
        int f = t & 127;
        float mean = bns[f] * (1.f / 8192.f);
        float var  = bns[128 + f] * (1.f / 8192.f) - mean * mean;
        float sc = rsqrtf(var + 1e-5f) * gamma[f];
        float sh = beta[f];
        int rb = t >> 7;
#pragma unroll
        for (int p = 0; p < 8; ++p) {
            int row = rb + p * 2;
            float x = H[(size_t)(r0 + row) * DIN + f];
            Hn[row * 128 + f] = (x - mean) * sc + sh;
        }
    }
    __syncthreads();
    {   // Hx = Hn @ Wt + bt : thread -> 4 rows x 4 cols
        int c0 = t & 63, rg = t >> 6;
        float acc[4][4];
#pragma unroll
        for (int i = 0; i < 4; ++i)
#pragma unroll
            for (int j = 0; j < 4; ++j) acc[i][j] = 0.f;
        for (int k = 0; k < 128; ++k) {
            float h[4];
#pragma unroll
            for (int rr = 0; rr < 4; ++rr) h[rr] = Hn[(rg * 4 + rr) * 128 + k];
#pragma unroll
            for (int cc = 0; cc < 4; ++cc) {
                float wv = Wt[k * DTH + c0 + 64 * cc];
#pragma unroll
                for (int rr = 0; rr < 4; ++rr) acc[rr][cc] += h[rr] * wv;
            }
        }
#pragma unroll
        for (int rr = 0; rr < 4; ++rr) {
            int row = r0 + rg * 4 + rr;
#pragma unroll
            for (int cc = 0; cc < 4; ++cc) {
                int c = c0 + 64 * cc;
                Hx[(size_t)row * DTH + c] = (bf16)(acc[rr][cc] + bt[c]);
            }
        }
    }
    {   // out1 (fp32 exact) and X2T (bf16)
        int c = t & 63, rg = t >> 6;
        float a1[4] = {0,0,0,0}, a2[4] = {0,0,0,0};
        for (int k = 0; k < 128; ++k) {
            float w1 = W1[k * DH + c], w2 = W2[k * DH + c];
#pragma unroll
            for (int rr = 0; rr < 4; ++rr) {
                float h = Hn[(rg * 4 + rr) * 128 + k];
                a1[rr] += h * w1; a2[rr] += h * w2;
            }
        }
#pragma unroll
        for (int rr = 0; rr < 4; ++rr) {
            int row = r0 + rg * 4 + rr;
            float v1 = a1[rr] + b1[c];
            out[(size_t)row * 128 + c] = v1 > 0.f ? v1 : 0.01f * v1;
            X2T[(size_t)c * NN + row] = (bf16)(a2[rr] + b2[c]);
        }
    }
}

// ---------------------------------------------------------------------------
// Fused v9 = round-0 kernel (155us best-known) with ONE change: the per-chunk
// A gate values come from the 8 MB L2-resident bitmask (8 broadcast u32 loads
// per lane) instead of 8 scattered dwords of the 256 MB A matrix. The A
// stream now runs in k_pack at full HBM rate instead of pacing this kernel.
// Mask word for (row ig, col jc): Am_u32[ig*256 + (jc>>6)*2 + ((jc>>5)&1)],
// bit jc&31; here jc = js*4096 + ch*64 + w*16 + li.
#define LDH 264   // Hx tile LDS row stride (256 + 8 pad, keeps 16B align)
#define LDP 72    // P / X2T LDS row stride (64 + 8 pad)

__global__ __launch_bounds__(256) void k_fused(
    const unsigned* __restrict__ Amask, const bf16* __restrict__ Hx,
    const bf16* __restrict__ X2T, float* __restrict__ pacc,
    float* __restrict__ pden)
{
    __shared__ __align__(16) bf16 hxi[32 * LDH];   // reused as P after prologue
    __shared__ __align__(16) bf16 hxj[64 * LDH];
    __shared__ __align__(16) bf16 x2t[64 * LDP];
    bf16* P = hxi;

    int t = threadIdx.x;
    int w = t >> 6, l = t & 63;
    int q = l >> 4, li = l & 15;
    int ib = blockIdx.x >> 1, js = blockIdx.x & 1;
    int i0 = ib * 32;
    int jbase = js * 4096;
    unsigned bsh = (w & 1) * 16 + li;   // bit within the u32 mask word

    // stage Hx_i (32 rows x 256) then preload A-fragments into registers
#pragma unroll
    for (int p = 0; p < 4; ++p) {
        int u = t + p * 256;
        int row = u >> 5, seg = u & 31;
        *(bf16x8*)&hxi[row * LDH + seg * 8] =
            *(const bf16x8*)&Hx[(size_t)(i0 + row) * DTH + seg * 8];
    }
    __syncthreads();
    bf16x8 afrag[2][8];
#pragma unroll
    for (int mb = 0; mb < 2; ++mb)
#pragma unroll
        for (int k = 0; k < 8; ++k)
            afrag[mb][k] = *(const bf16x8*)&hxi[(mb * 16 + li) * LDH + k * 32 + q * 8];
    __syncthreads();   // hxi region now free -> becomes P

    f32x4 agg[2] = {{0,0,0,0},{0,0,0,0}};
    float dpart[8] = {0,0,0,0,0,0,0,0};
    int mb_a = w >> 1, cb0 = (w & 1) * 2;

    // mask-word prefetch registers (2 chunks deep, compile-time ping-pong)
    unsigned mwA[8], mwB[8];
#define LOAD_MW(DST, CH) {                                                     \
        int wi_ = (js * 64 + (CH)) * 2 + (w >> 1);                             \
        _Pragma("unroll")                                                      \
        for (int mb = 0; mb < 2; ++mb)                                         \
            _Pragma("unroll")                                                  \
            for (int r = 0; r < 4; ++r)                                        \
                DST[mb * 4 + r] =                                              \
                    Amask[(size_t)(i0 + mb * 16 + q * 4 + r) * 256 + wi_];     \
    }
    LOAD_MW(mwA, 0)
    LOAD_MW(mwB, 1)

    // one 64-j chunk; MWC = this chunk's mask words (refilled for CH+2)
#define CHUNK(CH, MWC) {                                                       \
        int j0 = jbase + (CH) * 64;                                            \
        /* stage Hx_j chunk (64 rows x 256) */                                 \
        _Pragma("unroll")                                                      \
        for (int p = 0; p < 8; ++p) {                                          \
            int u = t + p * 256;                                               \
            int row = u >> 5, seg = u & 31;                                    \
            *(bf16x8*)&hxj[row * LDH + seg * 8] =                              \
                *(const bf16x8*)&Hx[(size_t)(j0 + row) * DTH + seg * 8];       \
        }                                                                      \
        /* stage X2 chunk transposed: x2t[col][j-local] */                     \
        _Pragma("unroll")                                                      \
        for (int p = 0; p < 2; ++p) {                                          \
            int u = t + p * 256;                                               \
            int c = u >> 3, seg = u & 7;                                       \
            *(bf16x8*)&x2t[c * LDP + seg * 8] =                                \
                *(const bf16x8*)&X2T[(size_t)c * NN + j0 + seg * 8];           \
        }                                                                      \
        __syncthreads();                                                       \
        /* S tiles: wave w covers n-tile w, both m-tiles, K=256 */             \
        f32x4 s0 = {0,0,0,0}, s1 = {0,0,0,0};                                  \
        _Pragma("unroll")                                                      \
        for (int k = 0; k < 8; ++k) {                                          \
            bf16x8 bfrag = *(const bf16x8*)&hxj[(w * 16 + li) * LDH + k * 32 + q * 8]; \
            s0 = __builtin_amdgcn_mfma_f32_16x16x32_bf16(afrag[0][k], bfrag, s0, 0, 0, 0); \
            s1 = __builtin_amdgcn_mfma_f32_16x16x32_bf16(afrag[1][k], bfrag, s1, 0, 0, 0); \
        }                                                                      \
        /* gate + exp, accumulate denom, write P (row-major LDS) */            \
        {                                                                      \
            int jc = j0 + w * 16 + li;                                         \
            _Pragma("unroll")                                                  \
            for (int mb = 0; mb < 2; ++mb) {                                   \
                f32x4 sv = mb ? s1 : s0;                                       \
                _Pragma("unroll")                                              \
                for (int r = 0; r < 4; ++r) {                                  \
                    int ig = i0 + mb * 16 + q * 4 + r;                         \
                    float s = sv[r];                                           \
                    float sig = __builtin_amdgcn_rcpf(1.f + __expf(-s));       \
                    float wv = ((MWC[mb * 4 + r] >> bsh) & 1u) ? __expf(sig) : 0.f; \
                    if (ig == jc) wv = 2.71828182845904523f;   /* exp(1) */    \
                    dpart[mb * 4 + r] += wv;                                   \
                    P[(mb * 16 + q * 4 + r) * LDP + w * 16 + li] = (bf16)wv;   \
                }                                                              \
            }                                                                  \
        }                                                                      \
        __syncthreads();   /* P visible to all waves */                        \
        /* prefetch mask words for chunk CH+2 (L2-resident, cheap) */          \
        { int c2 = ((CH) + 2 <= 63) ? (CH) + 2 : 63; LOAD_MW(MWC, c2) }        \
        /* agg += P @ X2chunk */                                               \
        _Pragma("unroll")                                                      \
        for (int ks = 0; ks < 2; ++ks) {                                       \
            bf16x8 pa = *(const bf16x8*)&P[(mb_a * 16 + li) * LDP + ks * 32 + q * 8]; \
            _Pragma("unroll")                                                  \
            for (int cbi = 0; cbi < 2; ++cbi) {                                \
                bf16x8 xb = *(const bf16x8*)&x2t[((cb0 + cbi) * 16 + li) * LDP + ks * 32 + q * 8]; \
                agg[cbi] = __builtin_amdgcn_mfma_f32_16x16x32_bf16(pa, xb, agg[cbi], 0, 0, 0); \
            }                                                                  \
        }                                                                      \
        __syncthreads();   /* all LDS reads done before next staging */        \
    }

    for (int ch = 0; ch < 64; ch += 2) {
        CHUNK(ch, mwA)
        CHUNK(ch + 1, mwB)
    }
#undef CHUNK
#undef LOAD_MW

    // write partial aggregation (each output element owned by 1 wave/block)
#pragma unroll
    for (int cbi = 0; cbi < 2; ++cbi)
#pragma unroll
        for (int r = 0; r < 4; ++r)
            atomicAdd(&pacc[(size_t)(i0 + mb_a * 16 + q * 4 + r) * DH + (cb0 + cbi) * 16 + li],
                      agg[cbi][r]);
    // reduce denom partials across the 16 lanes of each quad-group
#pragma unroll
    for (int idx = 0; idx < 8; ++idx) {
        float v = dpart[idx];
        v += __shfl_xor(v, 1, 64);
        v += __shfl_xor(v, 2, 64);
        v += __shfl_xor(v, 4, 64);
        v += __shfl_xor(v, 8, 64);
        if (li == 0)
            atomicAdd(&pden[i0 + (idx >> 2) * 16 + q * 4 + (idx & 3)], v);
    }
}

// ---------------------------------------------------------------------------
__global__ __launch_bounds__(256) void k_finalize(const float* __restrict__ pacc,
                                                  const float* __restrict__ pden,
                                                  float* __restrict__ out)
{
    int e = blockIdx.x * 256 + threadIdx.x;
    int i = e >> 6, c = e & 63;
    float v = pacc[e] / pden[i];
    out[(size_t)i * 128 + 64 + c] = v > 0.f ? v : 0.01f * v;
}

// ---------------------------------------------------------------------------
extern "C" void kernel_launch(void* const* d_in, const int* in_sizes, int n_in,
                              void* d_out, int out_size, void* d_ws, size_t ws_size,
                              hipStream_t stream)
{
    const float* H     = (const float*)d_in[0];
    const float* A     = (const float*)d_in[1];
    const float* gamma = (const float*)d_in[2];
    const float* beta  = (const float*)d_in[3];
    const float* Wt    = (const float*)d_in[4];
    const float* bt    = (const float*)d_in[5];
    const float* W1    = (const float*)d_in[6];
    const float* b1    = (const float*)d_in[7];
    const float* W2    = (const float*)d_in[8];
    const float* b2    = (const float*)d_in[9];
    float* out = (float*)d_out;

    char* ws = (char*)d_ws;
    float* pacc = (float*)(ws + OFF_PACC);
    float* pden = (float*)(ws + OFF_PDEN);
    float* bns  = (float*)(ws + OFF_BN);
    bf16*  Hx   = (bf16*)(ws + OFF_HX);
    bf16*  X2T  = (bf16*)(ws + OFF_X2T);
    unsigned long long* Am = (unsigned long long*)(ws + OFF_AM);

    hipMemsetAsync(ws, 0, ZERO_BYTES, stream);
    k_pack<<<8192, 256, 0, stream>>>(A, Am);
    k_bn_stats<<<256, 256, 0, stream>>>(H, bns);
    k_project<<<512, 256, 0, stream>>>(H, bns, gamma, beta, Wt, bt, W1, b1, W2, b2,
                                       Hx, X2T, out);
    k_fused<<<512, 256, 0, stream>>>((const unsigned*)Am, Hx, X2T, pacc, pden);
    k_finalize<<<2048, 256, 0, stream>>>(pacc, pden, out);
}